// Round 1
// baseline (1044.401 us; speedup 1.0000x reference)
//
#include <hip/hip_runtime.h>

// GraphEncoder: 2-layer GATConv (edge_dim=4, heads=4, concat) on MI355X.
// N=50000, E=800000, IN=16, C1=64 (H*C1=256), C2=32 (H*C2=128).
//
// Key simplification: edge embeddings eh=ea@We only appear via dot with
// a_edge => precompute Ve[4x4] per layer, a_e = ea @ Ve. Never build eh.

#define NEG_SLOPE 0.2f

__device__ __forceinline__ float lrelu(float v) { return v > 0.f ? v : NEG_SLOPE * v; }

// Ve1[d][h] = sum_c We1[d, h*64+c] * ae1[h,c];  Ve2 likewise with C=32.
__global__ void ve_kernel(const float* __restrict__ We1, const float* __restrict__ ae1,
                          const float* __restrict__ We2, const float* __restrict__ ae2,
                          float* __restrict__ Ve) {
    int t = threadIdx.x;
    if (t < 16) {
        int d = t >> 2, h = t & 3;
        float s = 0.f;
        for (int c = 0; c < 64; ++c) s += We1[d * 256 + h * 64 + c] * ae1[h * 64 + c];
        Ve[t] = s;
    } else if (t < 32) {
        int tt = t - 16;
        int d = tt >> 2, h = tt & 3;
        float s = 0.f;
        for (int c = 0; c < 32; ++c) s += We2[d * 128 + h * 32 + c] * ae2[h * 32 + c];
        Ve[16 + tt] = s;
    }
}

// in-degree histogram + sum of edge_attr per dst (for self-loop 'mean' fill).
__global__ void hist_kernel(const int* __restrict__ dst, const float* __restrict__ ea,
                            int* __restrict__ cnt, float* __restrict__ sum_ea, int E) {
    int e = blockIdx.x * blockDim.x + threadIdx.x;
    if (e >= E) return;
    int d = dst[e];
    atomicAdd(&cnt[d], 1);
#pragma unroll
    for (int k = 0; k < 4; ++k) atomicAdd(&sum_ea[d * 4 + k], ea[e * 4 + k]);
}

// exclusive scan of cnt -> off (CSR row offsets). Single block, chunked.
__global__ void scan_kernel(const int* __restrict__ cnt, int* __restrict__ off, int n) {
    __shared__ int sdata[1024];
    int tid = threadIdx.x;
    int running = 0;
    if (tid == 0) off[0] = 0;
    for (int base = 0; base < n; base += 1024) {
        int i = base + tid;
        int v = (i < n) ? cnt[i] : 0;
        __syncthreads();
        sdata[tid] = v;
        __syncthreads();
        for (int o = 1; o < 1024; o <<= 1) {
            int t = (tid >= o) ? sdata[tid - o] : 0;
            __syncthreads();
            sdata[tid] += t;
            __syncthreads();
        }
        if (i < n) off[i + 1] = running + sdata[tid];
        running += sdata[1023];
    }
}

// loop_ea = sum_ea / max(cnt,1) (in place); aeloopL[n][h] = loop_ea[n] . VeL[:,h]
__global__ void loop_kernel(const int* __restrict__ cnt, float* __restrict__ sum_ea,
                            const float* __restrict__ Ve,
                            float* __restrict__ aeloop1, float* __restrict__ aeloop2, int n) {
    int i = blockIdx.x * blockDim.x + threadIdx.x;
    if (i >= n) return;
    int c = cnt[i];
    float inv = 1.f / (float)(c > 0 ? c : 1);
    float la[4];
#pragma unroll
    for (int k = 0; k < 4; ++k) { la[k] = sum_ea[i * 4 + k] * inv; sum_ea[i * 4 + k] = la[k]; }
#pragma unroll
    for (int h = 0; h < 4; ++h) {
        float s1 = 0.f, s2 = 0.f;
#pragma unroll
        for (int d = 0; d < 4; ++d) { s1 += la[d] * Ve[d * 4 + h]; s2 += la[d] * Ve[16 + d * 4 + h]; }
        aeloop1[i * 4 + h] = s1;
        aeloop2[i * 4 + h] = s2;
    }
}

// counting-sort edges by dst; store src and per-layer a_e at sorted position.
__global__ void scatter_kernel(const int* __restrict__ src, const int* __restrict__ dst,
                               const float* __restrict__ ea, const int* __restrict__ off,
                               int* __restrict__ fill, const float* __restrict__ Ve,
                               int* __restrict__ src_sorted, float* __restrict__ ae1s,
                               float* __restrict__ ae2s, int E) {
    int e = blockIdx.x * blockDim.x + threadIdx.x;
    if (e >= E) return;
    int d = dst[e];
    int pos = off[d] + atomicAdd(&fill[d], 1);
    src_sorted[pos] = src[e];
    float e4[4];
#pragma unroll
    for (int k = 0; k < 4; ++k) e4[k] = ea[e * 4 + k];
#pragma unroll
    for (int h = 0; h < 4; ++h) {
        float s1 = 0.f, s2 = 0.f;
#pragma unroll
        for (int k = 0; k < 4; ++k) { s1 += e4[k] * Ve[k * 4 + h]; s2 += e4[k] * Ve[16 + k * 4 + h]; }
        ae1s[pos * 4 + h] = s1;
        ae2s[pos * 4 + h] = s2;
    }
}

// xh1 = x @ W1 ([N,16]@[16,256]); fused a_s1[n,h]=xh.as1, a_d1[n,h]=xh.ad1.
// 8 rows per block, 256 threads (one output column each). Head h == wave id.
__global__ void gemm1_kernel(const float* __restrict__ x, const float* __restrict__ W1,
                             const float* __restrict__ as1, const float* __restrict__ ad1,
                             float* __restrict__ xh1, float* __restrict__ a_s,
                             float* __restrict__ a_d, int N) {
    constexpr int R = 8;
    __shared__ float sx[R * 16];
    int n0 = blockIdx.x * R;
    int j = threadIdx.x;
    for (int idx = j; idx < R * 16; idx += 256) {
        int r = idx >> 4, k = idx & 15;
        int nn = n0 + r;
        sx[idx] = (nn < N) ? x[nn * 16 + k] : 0.f;
    }
    __syncthreads();
    float acc[R];
#pragma unroll
    for (int r = 0; r < R; ++r) acc[r] = 0.f;
#pragma unroll
    for (int k = 0; k < 16; ++k) {
        float w = W1[k * 256 + j];
#pragma unroll
        for (int r = 0; r < R; ++r) acc[r] += sx[r * 16 + k] * w;
    }
    float as = as1[j], ad = ad1[j];
    int h = j >> 6;
#pragma unroll
    for (int r = 0; r < R; ++r) {
        int nn = n0 + r;
        if (nn < N) xh1[(size_t)nn * 256 + j] = acc[r];
        float va = acc[r] * as, vd = acc[r] * ad;
#pragma unroll
        for (int o = 32; o > 0; o >>= 1) {
            va += __shfl_xor(va, o, 64);
            vd += __shfl_xor(vd, o, 64);
        }
        if ((j & 63) == 0 && nn < N) { a_s[nn * 4 + h] = va; a_d[nn * 4 + h] = vd; }
    }
}

// xh2 = h1 @ W2 ([N,256]@[256,128]); fused a_s2/a_d2 (heads are 32-lane groups).
// 16 rows per block, 128 threads.
__global__ void gemm2_kernel(const float* __restrict__ h1, const float* __restrict__ W2,
                             const float* __restrict__ as2, const float* __restrict__ ad2,
                             float* __restrict__ xh2, float* __restrict__ a_s,
                             float* __restrict__ a_d, int N) {
    constexpr int R = 16;
    __shared__ float sh[R * 256];
    int n0 = blockIdx.x * R;
    int j = threadIdx.x;
    for (int idx = j; idx < R * 256; idx += 128) {
        int r = idx >> 8, k = idx & 255;
        int nn = n0 + r;
        sh[idx] = (nn < N) ? h1[(size_t)nn * 256 + k] : 0.f;
    }
    __syncthreads();
    float acc[R];
#pragma unroll
    for (int r = 0; r < R; ++r) acc[r] = 0.f;
    for (int k = 0; k < 256; ++k) {
        float w = W2[k * 128 + j];
#pragma unroll
        for (int r = 0; r < R; ++r) acc[r] += sh[r * 256 + k] * w;
    }
    float as = as2[j], ad = ad2[j];
    int h = j >> 5;
#pragma unroll
    for (int r = 0; r < R; ++r) {
        int nn = n0 + r;
        if (nn < N) xh2[(size_t)nn * 128 + j] = acc[r];
        float va = acc[r] * as, vd = acc[r] * ad;
#pragma unroll
        for (int o = 16; o > 0; o >>= 1) {
            va += __shfl_xor(va, o, 32);
            vd += __shfl_xor(vd, o, 32);
        }
        if ((j & 31) == 0 && nn < N) { a_s[nn * 4 + h] = va; a_d[nn * 4 + h] = vd; }
    }
}

// Per-node segment softmax + weighted gather-aggregate.
// One block per node, one thread per output channel (CT = H*C).
// Two passes over CSR edge list: (1) max logit, (2) exp-sum + gather xh[src].
template <int CT, int C>
__global__ void agg_kernel(const int* __restrict__ off, const int* __restrict__ srcs,
                           const float* __restrict__ aes, const float* __restrict__ aeloop,
                           const float* __restrict__ a_s, const float* __restrict__ a_d,
                           const float* __restrict__ xh, const float* __restrict__ bias,
                           float* __restrict__ out, int relu) {
    int n = blockIdx.x;
    int j = threadIdx.x;
    int h = j / C;
    float ad = a_d[n * 4 + h];
    int beg = off[n], end = off[n + 1];

    float lself = lrelu(a_s[n * 4 + h] + ad + aeloop[n * 4 + h]);
    float m = lself;
    for (int i = beg; i < end; ++i) {
        int s = srcs[i];
        float lg = lrelu(a_s[s * 4 + h] + ad + aes[i * 4 + h]);
        m = fmaxf(m, lg);
    }
    float ex = expf(lself - m);
    float den = ex;
    float acc = ex * xh[(size_t)n * CT + j];
    for (int i = beg; i < end; ++i) {
        int s = srcs[i];
        float lg = lrelu(a_s[s * 4 + h] + ad + aes[i * 4 + h]);
        float e2 = expf(lg - m);
        den += e2;
        acc += e2 * xh[(size_t)s * CT + j];
    }
    float o = acc / den + bias[j];
    if (relu) o = fmaxf(o, 0.f);
    out[(size_t)n * CT + j] = o;
}

extern "C" void kernel_launch(void* const* d_in, const int* in_sizes, int n_in,
                              void* d_out, int out_size, void* d_ws, size_t ws_size,
                              hipStream_t stream) {
    const float* x   = (const float*)d_in[0];
    const int*   ei  = (const int*)d_in[1];
    const float* ea  = (const float*)d_in[2];
    const float* W1  = (const float*)d_in[3];
    const float* We1 = (const float*)d_in[4];
    const float* as1 = (const float*)d_in[5];
    const float* ad1 = (const float*)d_in[6];
    const float* ae1 = (const float*)d_in[7];
    const float* b1  = (const float*)d_in[8];
    const float* W2  = (const float*)d_in[9];
    const float* We2 = (const float*)d_in[10];
    const float* as2 = (const float*)d_in[11];
    const float* ad2 = (const float*)d_in[12];
    const float* ae2 = (const float*)d_in[13];
    const float* b2  = (const float*)d_in[14];
    float* out = (float*)d_out;

    const int N = in_sizes[0] / 16;
    const int E = in_sizes[1] / 2;
    const int* srcp = ei;
    const int* dstp = ei + E;

    char* w = (char*)d_ws;
    size_t o = 0;
    auto alloc = [&](size_t bytes) -> void* {
        void* p = w + o;
        o += (bytes + 255) & ~(size_t)255;
        return p;
    };
    // zeroed prefix: cnt | fill | sum_ea (one memset covers all three)
    int*   cnt     = (int*)alloc((size_t)N * 4);
    int*   fill    = (int*)alloc((size_t)N * 4);
    float* sum_ea  = (float*)alloc((size_t)N * 16);
    size_t zero_bytes = o;
    int*   off_    = (int*)alloc((size_t)(N + 1) * 4);
    float* Ve      = (float*)alloc(32 * 4);
    float* aeloop1 = (float*)alloc((size_t)N * 16);
    float* aeloop2 = (float*)alloc((size_t)N * 16);
    float* a_s1    = (float*)alloc((size_t)N * 16);
    float* a_d1    = (float*)alloc((size_t)N * 16);
    float* a_s2    = (float*)alloc((size_t)N * 16);
    float* a_d2    = (float*)alloc((size_t)N * 16);
    int*   src_s   = (int*)alloc((size_t)E * 4);
    float* ae1s    = (float*)alloc((size_t)E * 16);
    float* ae2s    = (float*)alloc((size_t)E * 16);
    float* xh1     = (float*)alloc((size_t)N * 256 * 4);
    float* h1      = (float*)alloc((size_t)N * 256 * 4);
    float* xh2     = xh1;  // xh1 dead after agg1; reuse for xh2 ([N,128] fits)

    hipMemsetAsync(d_ws, 0, zero_bytes, stream);
    ve_kernel<<<1, 64, 0, stream>>>(We1, ae1, We2, ae2, Ve);
    hist_kernel<<<(E + 255) / 256, 256, 0, stream>>>(dstp, ea, cnt, sum_ea, E);
    scan_kernel<<<1, 1024, 0, stream>>>(cnt, off_, N);
    loop_kernel<<<(N + 255) / 256, 256, 0, stream>>>(cnt, sum_ea, Ve, aeloop1, aeloop2, N);
    scatter_kernel<<<(E + 255) / 256, 256, 0, stream>>>(srcp, dstp, ea, off_, fill, Ve,
                                                        src_s, ae1s, ae2s, E);
    // layer 1
    gemm1_kernel<<<(N + 7) / 8, 256, 0, stream>>>(x, W1, as1, ad1, xh1, a_s1, a_d1, N);
    agg_kernel<256, 64><<<N, 256, 0, stream>>>(off_, src_s, ae1s, aeloop1, a_s1, a_d1,
                                               xh1, b1, h1, 1);
    // layer 2
    gemm2_kernel<<<(N + 15) / 16, 128, 0, stream>>>(h1, W2, as2, ad2, xh2, a_s2, a_d2, N);
    agg_kernel<128, 32><<<N, 128, 0, stream>>>(off_, src_s, ae2s, aeloop2, a_s2, a_d2,
                                               xh2, b2, out, 0);
}

// Round 4
// 860.378 us; speedup vs baseline: 1.2139x; 1.2139x over previous
//
#include <hip/hip_runtime.h>

// GraphEncoder: 2-layer GATConv (edge_dim=4, heads=4, concat) on MI355X.
// N=50000, E=800000, IN=16, C1=64 (H*C1=256), C2=32 (H*C2=128).
//
// Key simplification: edge embeddings eh=ea@We only appear via dot with
// a_edge => precompute Ve[4x4] per layer, a_e = ea @ Ve. Never build eh.
//
// R1: agg_kernel was VALU-bound (86% VALUBusy) from 64x-redundant per-thread
// logit+expf. Now cooperative: logits/exp computed once per (edge,head) in
// LDS, phase-3 is a pure weighted gather.
// R2/R3: infra timeouts — resubmitting R1 source unchanged for measurement.

#define NEG_SLOPE 0.2f

__device__ __forceinline__ float lrelu(float v) { return v > 0.f ? v : NEG_SLOPE * v; }

// Ve1[d][h] = sum_c We1[d, h*64+c] * ae1[h,c];  Ve2 likewise with C=32.
__global__ void ve_kernel(const float* __restrict__ We1, const float* __restrict__ ae1,
                          const float* __restrict__ We2, const float* __restrict__ ae2,
                          float* __restrict__ Ve) {
    int t = threadIdx.x;
    if (t < 16) {
        int d = t >> 2, h = t & 3;
        float s = 0.f;
        for (int c = 0; c < 64; ++c) s += We1[d * 256 + h * 64 + c] * ae1[h * 64 + c];
        Ve[t] = s;
    } else if (t < 32) {
        int tt = t - 16;
        int d = tt >> 2, h = tt & 3;
        float s = 0.f;
        for (int c = 0; c < 32; ++c) s += We2[d * 128 + h * 32 + c] * ae2[h * 32 + c];
        Ve[16 + tt] = s;
    }
}

// in-degree histogram + sum of edge_attr per dst (for self-loop 'mean' fill).
__global__ void hist_kernel(const int* __restrict__ dst, const float* __restrict__ ea,
                            int* __restrict__ cnt, float* __restrict__ sum_ea, int E) {
    int e = blockIdx.x * blockDim.x + threadIdx.x;
    if (e >= E) return;
    int d = dst[e];
    atomicAdd(&cnt[d], 1);
#pragma unroll
    for (int k = 0; k < 4; ++k) atomicAdd(&sum_ea[d * 4 + k], ea[e * 4 + k]);
}

// exclusive scan of cnt -> off (CSR row offsets). Single block, chunked.
__global__ void scan_kernel(const int* __restrict__ cnt, int* __restrict__ off, int n) {
    __shared__ int sdata[1024];
    int tid = threadIdx.x;
    int running = 0;
    if (tid == 0) off[0] = 0;
    for (int base = 0; base < n; base += 1024) {
        int i = base + tid;
        int v = (i < n) ? cnt[i] : 0;
        __syncthreads();
        sdata[tid] = v;
        __syncthreads();
        for (int o = 1; o < 1024; o <<= 1) {
            int t = (tid >= o) ? sdata[tid - o] : 0;
            __syncthreads();
            sdata[tid] += t;
            __syncthreads();
        }
        if (i < n) off[i + 1] = running + sdata[tid];
        running += sdata[1023];
    }
}

// loop_ea = sum_ea / max(cnt,1) (in place); aeloopL[n][h] = loop_ea[n] . VeL[:,h]
__global__ void loop_kernel(const int* __restrict__ cnt, float* __restrict__ sum_ea,
                            const float* __restrict__ Ve,
                            float* __restrict__ aeloop1, float* __restrict__ aeloop2, int n) {
    int i = blockIdx.x * blockDim.x + threadIdx.x;
    if (i >= n) return;
    int c = cnt[i];
    float inv = 1.f / (float)(c > 0 ? c : 1);
    float la[4];
#pragma unroll
    for (int k = 0; k < 4; ++k) { la[k] = sum_ea[i * 4 + k] * inv; sum_ea[i * 4 + k] = la[k]; }
#pragma unroll
    for (int h = 0; h < 4; ++h) {
        float s1 = 0.f, s2 = 0.f;
#pragma unroll
        for (int d = 0; d < 4; ++d) { s1 += la[d] * Ve[d * 4 + h]; s2 += la[d] * Ve[16 + d * 4 + h]; }
        aeloop1[i * 4 + h] = s1;
        aeloop2[i * 4 + h] = s2;
    }
}

// counting-sort edges by dst; store src and per-layer a_e at sorted position.
__global__ void scatter_kernel(const int* __restrict__ src, const int* __restrict__ dst,
                               const float* __restrict__ ea, const int* __restrict__ off,
                               int* __restrict__ fill, const float* __restrict__ Ve,
                               int* __restrict__ src_sorted, float* __restrict__ ae1s,
                               float* __restrict__ ae2s, int E) {
    int e = blockIdx.x * blockDim.x + threadIdx.x;
    if (e >= E) return;
    int d = dst[e];
    int pos = off[d] + atomicAdd(&fill[d], 1);
    src_sorted[pos] = src[e];
    float e4[4];
#pragma unroll
    for (int k = 0; k < 4; ++k) e4[k] = ea[e * 4 + k];
#pragma unroll
    for (int h = 0; h < 4; ++h) {
        float s1 = 0.f, s2 = 0.f;
#pragma unroll
        for (int k = 0; k < 4; ++k) { s1 += e4[k] * Ve[k * 4 + h]; s2 += e4[k] * Ve[16 + k * 4 + h]; }
        ae1s[pos * 4 + h] = s1;
        ae2s[pos * 4 + h] = s2;
    }
}

// xh1 = x @ W1 ([N,16]@[16,256]); fused a_s1[n,h]=xh.as1, a_d1[n,h]=xh.ad1.
__global__ void gemm1_kernel(const float* __restrict__ x, const float* __restrict__ W1,
                             const float* __restrict__ as1, const float* __restrict__ ad1,
                             float* __restrict__ xh1, float* __restrict__ a_s,
                             float* __restrict__ a_d, int N) {
    constexpr int R = 8;
    __shared__ float sx[R * 16];
    int n0 = blockIdx.x * R;
    int j = threadIdx.x;
    for (int idx = j; idx < R * 16; idx += 256) {
        int r = idx >> 4, k = idx & 15;
        int nn = n0 + r;
        sx[idx] = (nn < N) ? x[nn * 16 + k] : 0.f;
    }
    __syncthreads();
    float acc[R];
#pragma unroll
    for (int r = 0; r < R; ++r) acc[r] = 0.f;
#pragma unroll
    for (int k = 0; k < 16; ++k) {
        float w = W1[k * 256 + j];
#pragma unroll
        for (int r = 0; r < R; ++r) acc[r] += sx[r * 16 + k] * w;
    }
    float as = as1[j], ad = ad1[j];
    int h = j >> 6;
#pragma unroll
    for (int r = 0; r < R; ++r) {
        int nn = n0 + r;
        if (nn < N) xh1[(size_t)nn * 256 + j] = acc[r];
        float va = acc[r] * as, vd = acc[r] * ad;
#pragma unroll
        for (int o = 32; o > 0; o >>= 1) {
            va += __shfl_xor(va, o, 64);
            vd += __shfl_xor(vd, o, 64);
        }
        if ((j & 63) == 0 && nn < N) { a_s[nn * 4 + h] = va; a_d[nn * 4 + h] = vd; }
    }
}

// xh2 = h1 @ W2 ([N,256]@[256,128]); fused a_s2/a_d2 (heads are 32-lane groups).
__global__ void gemm2_kernel(const float* __restrict__ h1, const float* __restrict__ W2,
                             const float* __restrict__ as2, const float* __restrict__ ad2,
                             float* __restrict__ xh2, float* __restrict__ a_s,
                             float* __restrict__ a_d, int N) {
    constexpr int R = 16;
    __shared__ float sh[R * 256];
    int n0 = blockIdx.x * R;
    int j = threadIdx.x;
    for (int idx = j; idx < R * 256; idx += 128) {
        int r = idx >> 8, k = idx & 255;
        int nn = n0 + r;
        sh[idx] = (nn < N) ? h1[(size_t)nn * 256 + k] : 0.f;
    }
    __syncthreads();
    float acc[R];
#pragma unroll
    for (int r = 0; r < R; ++r) acc[r] = 0.f;
    for (int k = 0; k < 256; ++k) {
        float w = W2[k * 128 + j];
#pragma unroll
        for (int r = 0; r < R; ++r) acc[r] += sh[r * 256 + k] * w;
    }
    float as = as2[j], ad = ad2[j];
    int h = j >> 5;
#pragma unroll
    for (int r = 0; r < R; ++r) {
        int nn = n0 + r;
        if (nn < N) xh2[(size_t)nn * 128 + j] = acc[r];
        float va = acc[r] * as, vd = acc[r] * ad;
#pragma unroll
        for (int o = 16; o > 0; o >>= 1) {
            va += __shfl_xor(va, o, 32);
            vd += __shfl_xor(vd, o, 32);
        }
        if ((j & 31) == 0 && nn < N) { a_s[nn * 4 + h] = va; a_d[nn * 4 + h] = vd; }
    }
}

// Per-node segment softmax + weighted gather-aggregate, cooperative version.
// One block per node. Phase 1: per-edge logits (x4 heads) computed once into
// LDS (self-loop appended as edge deg). Phase 2: per-head max/exp/den,
// cooperative + shfl reduce. Phase 3: per-thread weighted gather of xh[src].
template <int CT, int C>
__global__ __launch_bounds__(CT) void agg_kernel(
        const int* __restrict__ off, const int* __restrict__ srcs,
        const float* __restrict__ aes, const float* __restrict__ aeloop,
        const float* __restrict__ a_s, const float* __restrict__ a_d,
        const float* __restrict__ xh, const float* __restrict__ bias,
        float* __restrict__ out, int relu) {
    constexpr int CAP = 512;        // max edges (incl. self) staged in LDS
    constexpr int NW  = CT / 64;    // waves per block
    constexpr int TPG = CT / 4;     // threads per head in phase 2
    __shared__ int   s_src[CAP];
    __shared__ float s_lg[CAP * 4];
    __shared__ float s_wred[NW * 4];
    __shared__ float s_m[4];
    __shared__ float s_den[4];

    int n = blockIdx.x;
    int j = threadIdx.x;
    int beg = off[n], end = off[n + 1];
    int deg = end - beg;
    int tot = deg + 1;  // + self loop
    int h = j / C;

    const float4 ad4 = *(const float4*)&a_d[(size_t)n * 4];

    if (tot <= CAP) {
        // ---- phase 1: logits, one edge per thread ----
        for (int idx = j; idx < tot; idx += CT) {
            int s; float4 ae;
            if (idx < deg) {
                s  = srcs[beg + idx];
                ae = *(const float4*)&aes[(size_t)(beg + idx) * 4];
            } else {
                s  = n;
                ae = *(const float4*)&aeloop[(size_t)n * 4];
            }
            s_src[idx] = s;
            float4 as4 = *(const float4*)&a_s[(size_t)s * 4];
            s_lg[idx * 4 + 0] = lrelu(as4.x + ad4.x + ae.x);
            s_lg[idx * 4 + 1] = lrelu(as4.y + ad4.y + ae.y);
            s_lg[idx * 4 + 2] = lrelu(as4.z + ad4.z + ae.z);
            s_lg[idx * 4 + 3] = lrelu(as4.w + ad4.w + ae.w);
        }
        __syncthreads();
        // ---- phase 2: per-head max, exp, denominator ----
        int lane = j & 63, w = j >> 6;
        int g = j & 3, r = j >> 2;
        float m = -3.4e38f;
        for (int i = r; i < tot; i += TPG) m = fmaxf(m, s_lg[i * 4 + g]);
#pragma unroll
        for (int o = 4; o < 64; o <<= 1) m = fmaxf(m, __shfl_xor(m, o, 64));
        if (lane < 4) s_wred[w * 4 + lane] = m;
        __syncthreads();
        if (j < 4) {
            float mm = s_wred[j];
            for (int ww = 1; ww < NW; ++ww) mm = fmaxf(mm, s_wred[ww * 4 + j]);
            s_m[j] = mm;
        }
        __syncthreads();
        float mh = s_m[g];
        float den = 0.f;
        for (int i = r; i < tot; i += TPG) {
            float e = expf(s_lg[i * 4 + g] - mh);
            s_lg[i * 4 + g] = e;
            den += e;
        }
#pragma unroll
        for (int o = 4; o < 64; o <<= 1) den += __shfl_xor(den, o, 64);
        if (lane < 4) s_wred[w * 4 + lane] = den;
        __syncthreads();
        if (j < 4) {
            float dd = s_wred[j];
            for (int ww = 1; ww < NW; ++ww) dd += s_wred[ww * 4 + j];
            s_den[j] = dd;
        }
        __syncthreads();
        // ---- phase 3: weighted gather ----
        float invden = 1.f / s_den[h];
        float acc = 0.f;
        int i = 0;
        for (; i + 1 < tot; i += 2) {
            float w0 = s_lg[i * 4 + h], w1 = s_lg[(i + 1) * 4 + h];
            int   s0 = s_src[i],        s1 = s_src[i + 1];
            float x0 = xh[(size_t)s0 * CT + j];
            float x1 = xh[(size_t)s1 * CT + j];
            acc += w0 * x0;
            acc += w1 * x1;
        }
        if (i < tot) acc += s_lg[i * 4 + h] * xh[(size_t)s_src[i] * CT + j];
        float o2 = acc * invden + bias[j];
        if (relu) o2 = fmaxf(o2, 0.f);
        out[(size_t)n * CT + j] = o2;
    } else {
        // ---- fallback (deg+1 > CAP): per-thread two-pass (correct, slow) ----
        float adh = ((const float*)&ad4)[h];
        float lself = lrelu(a_s[(size_t)n * 4 + h] + adh + aeloop[(size_t)n * 4 + h]);
        float m = lself;
        for (int i2 = beg; i2 < end; ++i2) {
            int s = srcs[i2];
            float lg = lrelu(a_s[(size_t)s * 4 + h] + adh + aes[(size_t)i2 * 4 + h]);
            m = fmaxf(m, lg);
        }
        float ex = expf(lself - m);
        float den = ex;
        float acc = ex * xh[(size_t)n * CT + j];
        for (int i2 = beg; i2 < end; ++i2) {
            int s = srcs[i2];
            float lg = lrelu(a_s[(size_t)s * 4 + h] + adh + aes[(size_t)i2 * 4 + h]);
            float e2 = expf(lg - m);
            den += e2;
            acc += e2 * xh[(size_t)s * CT + j];
        }
        float o2 = acc / den + bias[j];
        if (relu) o2 = fmaxf(o2, 0.f);
        out[(size_t)n * CT + j] = o2;
    }
}

extern "C" void kernel_launch(void* const* d_in, const int* in_sizes, int n_in,
                              void* d_out, int out_size, void* d_ws, size_t ws_size,
                              hipStream_t stream) {
    const float* x   = (const float*)d_in[0];
    const int*   ei  = (const int*)d_in[1];
    const float* ea  = (const float*)d_in[2];
    const float* W1  = (const float*)d_in[3];
    const float* We1 = (const float*)d_in[4];
    const float* as1 = (const float*)d_in[5];
    const float* ad1 = (const float*)d_in[6];
    const float* ae1 = (const float*)d_in[7];
    const float* b1  = (const float*)d_in[8];
    const float* W2  = (const float*)d_in[9];
    const float* We2 = (const float*)d_in[10];
    const float* as2 = (const float*)d_in[11];
    const float* ad2 = (const float*)d_in[12];
    const float* ae2 = (const float*)d_in[13];
    const float* b2  = (const float*)d_in[14];
    float* out = (float*)d_out;

    const int N = in_sizes[0] / 16;
    const int E = in_sizes[1] / 2;
    const int* srcp = ei;
    const int* dstp = ei + E;

    char* w = (char*)d_ws;
    size_t o = 0;
    auto alloc = [&](size_t bytes) -> void* {
        void* p = w + o;
        o += (bytes + 255) & ~(size_t)255;
        return p;
    };
    // zeroed prefix: cnt | fill | sum_ea (one memset covers all three)
    int*   cnt     = (int*)alloc((size_t)N * 4);
    int*   fill    = (int*)alloc((size_t)N * 4);
    float* sum_ea  = (float*)alloc((size_t)N * 16);
    size_t zero_bytes = o;
    int*   off_    = (int*)alloc((size_t)(N + 1) * 4);
    float* Ve      = (float*)alloc(32 * 4);
    float* aeloop1 = (float*)alloc((size_t)N * 16);
    float* aeloop2 = (float*)alloc((size_t)N * 16);
    float* a_s1    = (float*)alloc((size_t)N * 16);
    float* a_d1    = (float*)alloc((size_t)N * 16);
    float* a_s2    = (float*)alloc((size_t)N * 16);
    float* a_d2    = (float*)alloc((size_t)N * 16);
    int*   src_s   = (int*)alloc((size_t)E * 4);
    float* ae1s    = (float*)alloc((size_t)E * 16);
    float* ae2s    = (float*)alloc((size_t)E * 16);
    float* xh1     = (float*)alloc((size_t)N * 256 * 4);
    float* h1      = (float*)alloc((size_t)N * 256 * 4);
    float* xh2     = xh1;  // xh1 dead after agg1; reuse for xh2 ([N,128] fits)

    hipMemsetAsync(d_ws, 0, zero_bytes, stream);
    ve_kernel<<<1, 64, 0, stream>>>(We1, ae1, We2, ae2, Ve);
    hist_kernel<<<(E + 255) / 256, 256, 0, stream>>>(dstp, ea, cnt, sum_ea, E);
    scan_kernel<<<1, 1024, 0, stream>>>(cnt, off_, N);
    loop_kernel<<<(N + 255) / 256, 256, 0, stream>>>(cnt, sum_ea, Ve, aeloop1, aeloop2, N);
    scatter_kernel<<<(E + 255) / 256, 256, 0, stream>>>(srcp, dstp, ea, off_, fill, Ve,
                                                        src_s, ae1s, ae2s, E);
    // layer 1
    gemm1_kernel<<<(N + 7) / 8, 256, 0, stream>>>(x, W1, as1, ad1, xh1, a_s1, a_d1, N);
    agg_kernel<256, 64><<<N, 256, 0, stream>>>(off_, src_s, ae1s, aeloop1, a_s1, a_d1,
                                               xh1, b1, h1, 1);
    // layer 2
    gemm2_kernel<<<(N + 15) / 16, 128, 0, stream>>>(h1, W2, as2, ad2, xh2, a_s2, a_d2, N);
    agg_kernel<128, 32><<<N, 128, 0, stream>>>(off_, src_s, ae2s, aeloop2, a_s2, a_d2,
                                               xh2, b2, out, 0);
}

// Round 5
// 701.571 us; speedup vs baseline: 1.4887x; 1.2264x over previous
//
#include <hip/hip_runtime.h>

// GraphEncoder: 2-layer GATConv (edge_dim=4, heads=4, concat) on MI355X.
// N=50000, E=800000, IN=16, C1=64 (H*C1=256), C2=32 (H*C2=128).
//
// Key simplification: edge embeddings eh=ea@We only appear via dot with
// a_edge => precompute Ve[4x4] per layer, a_e = ea @ Ve. Never build eh.
//
// R1: agg_kernel cooperative (logits/exp once per edge-head in LDS) — 322->~140us.
// R4: hist_kernel was 193us, WRITE_SIZE=124MB from 4 scattered float atomics
// per edge. aeloop = (mean ea)@Ve = segment-mean of (ea@Ve) by linearity, so
// compute it from the sorted ae1s/ae2s after scatter. hist keeps only the
// int cnt atomic.

#define NEG_SLOPE 0.2f

__device__ __forceinline__ float lrelu(float v) { return v > 0.f ? v : NEG_SLOPE * v; }

// Ve1[d][h] = sum_c We1[d, h*64+c] * ae1[h,c];  Ve2 likewise with C=32.
__global__ void ve_kernel(const float* __restrict__ We1, const float* __restrict__ ae1,
                          const float* __restrict__ We2, const float* __restrict__ ae2,
                          float* __restrict__ Ve) {
    int t = threadIdx.x;
    if (t < 16) {
        int d = t >> 2, h = t & 3;
        float s = 0.f;
        for (int c = 0; c < 64; ++c) s += We1[d * 256 + h * 64 + c] * ae1[h * 64 + c];
        Ve[t] = s;
    } else if (t < 32) {
        int tt = t - 16;
        int d = tt >> 2, h = tt & 3;
        float s = 0.f;
        for (int c = 0; c < 32; ++c) s += We2[d * 128 + h * 32 + c] * ae2[h * 32 + c];
        Ve[16 + tt] = s;
    }
}

// in-degree histogram only (self-loop mean handled later from sorted ae).
__global__ void hist_kernel(const int* __restrict__ dst, int* __restrict__ cnt, int E) {
    int e = blockIdx.x * blockDim.x + threadIdx.x;
    if (e >= E) return;
    atomicAdd(&cnt[dst[e]], 1);
}

// exclusive scan of cnt -> off (CSR row offsets). Single block, chunked.
__global__ void scan_kernel(const int* __restrict__ cnt, int* __restrict__ off, int n) {
    __shared__ int sdata[1024];
    int tid = threadIdx.x;
    int running = 0;
    if (tid == 0) off[0] = 0;
    for (int base = 0; base < n; base += 1024) {
        int i = base + tid;
        int v = (i < n) ? cnt[i] : 0;
        __syncthreads();
        sdata[tid] = v;
        __syncthreads();
        for (int o = 1; o < 1024; o <<= 1) {
            int t = (tid >= o) ? sdata[tid - o] : 0;
            __syncthreads();
            sdata[tid] += t;
            __syncthreads();
        }
        if (i < n) off[i + 1] = running + sdata[tid];
        running += sdata[1023];
    }
}

// counting-sort edges by dst; store src and per-layer a_e at sorted position.
__global__ void scatter_kernel(const int* __restrict__ src, const int* __restrict__ dst,
                               const float* __restrict__ ea, const int* __restrict__ off,
                               int* __restrict__ fill, const float* __restrict__ Ve,
                               int* __restrict__ src_sorted, float* __restrict__ ae1s,
                               float* __restrict__ ae2s, int E) {
    int e = blockIdx.x * blockDim.x + threadIdx.x;
    if (e >= E) return;
    int d = dst[e];
    int pos = off[d] + atomicAdd(&fill[d], 1);
    src_sorted[pos] = src[e];
    float e4[4];
#pragma unroll
    for (int k = 0; k < 4; ++k) e4[k] = ea[e * 4 + k];
#pragma unroll
    for (int h = 0; h < 4; ++h) {
        float s1 = 0.f, s2 = 0.f;
#pragma unroll
        for (int k = 0; k < 4; ++k) { s1 += e4[k] * Ve[k * 4 + h]; s2 += e4[k] * Ve[16 + k * 4 + h]; }
        ae1s[pos * 4 + h] = s1;
        ae2s[pos * 4 + h] = s2;
    }
}

// aeloopL[n][h] = mean over n's incoming edges of aeLs (linearity of @Ve).
// 8 threads per node: k<4 -> layer1 head k, k>=4 -> layer2 head k-4.
__global__ void aeloop_kernel(const int* __restrict__ off,
                              const float* __restrict__ ae1s, const float* __restrict__ ae2s,
                              float* __restrict__ aeloop1, float* __restrict__ aeloop2, int n) {
    int t = blockIdx.x * blockDim.x + threadIdx.x;
    int node = t >> 3, k = t & 7;
    if (node >= n) return;
    int beg = off[node], end = off[node + 1];
    int deg = end - beg;
    float inv = 1.f / (float)(deg > 0 ? deg : 1);
    const float* srcp = (k < 4) ? ae1s : ae2s;
    int h = k & 3;
    float s = 0.f;
    for (int i = beg; i < end; ++i) s += srcp[(size_t)i * 4 + h];
    float* dstp = (k < 4) ? aeloop1 : aeloop2;
    dstp[(size_t)node * 4 + h] = s * inv;
}

// xh1 = x @ W1 ([N,16]@[16,256]); fused a_s1[n,h]=xh.as1, a_d1[n,h]=xh.ad1.
__global__ void gemm1_kernel(const float* __restrict__ x, const float* __restrict__ W1,
                             const float* __restrict__ as1, const float* __restrict__ ad1,
                             float* __restrict__ xh1, float* __restrict__ a_s,
                             float* __restrict__ a_d, int N) {
    constexpr int R = 8;
    __shared__ float sx[R * 16];
    int n0 = blockIdx.x * R;
    int j = threadIdx.x;
    for (int idx = j; idx < R * 16; idx += 256) {
        int r = idx >> 4, k = idx & 15;
        int nn = n0 + r;
        sx[idx] = (nn < N) ? x[nn * 16 + k] : 0.f;
    }
    __syncthreads();
    float acc[R];
#pragma unroll
    for (int r = 0; r < R; ++r) acc[r] = 0.f;
#pragma unroll
    for (int k = 0; k < 16; ++k) {
        float w = W1[k * 256 + j];
#pragma unroll
        for (int r = 0; r < R; ++r) acc[r] += sx[r * 16 + k] * w;
    }
    float as = as1[j], ad = ad1[j];
    int h = j >> 6;
#pragma unroll
    for (int r = 0; r < R; ++r) {
        int nn = n0 + r;
        if (nn < N) xh1[(size_t)nn * 256 + j] = acc[r];
        float va = acc[r] * as, vd = acc[r] * ad;
#pragma unroll
        for (int o = 32; o > 0; o >>= 1) {
            va += __shfl_xor(va, o, 64);
            vd += __shfl_xor(vd, o, 64);
        }
        if ((j & 63) == 0 && nn < N) { a_s[nn * 4 + h] = va; a_d[nn * 4 + h] = vd; }
    }
}

// xh2 = h1 @ W2 ([N,256]@[256,128]); fused a_s2/a_d2 (heads are 32-lane groups).
__global__ void gemm2_kernel(const float* __restrict__ h1, const float* __restrict__ W2,
                             const float* __restrict__ as2, const float* __restrict__ ad2,
                             float* __restrict__ xh2, float* __restrict__ a_s,
                             float* __restrict__ a_d, int N) {
    constexpr int R = 16;
    __shared__ float sh[R * 256];
    int n0 = blockIdx.x * R;
    int j = threadIdx.x;
    for (int idx = j; idx < R * 256; idx += 128) {
        int r = idx >> 8, k = idx & 255;
        int nn = n0 + r;
        sh[idx] = (nn < N) ? h1[(size_t)nn * 256 + k] : 0.f;
    }
    __syncthreads();
    float acc[R];
#pragma unroll
    for (int r = 0; r < R; ++r) acc[r] = 0.f;
    for (int k = 0; k < 256; ++k) {
        float w = W2[k * 128 + j];
#pragma unroll
        for (int r = 0; r < R; ++r) acc[r] += sh[r * 256 + k] * w;
    }
    float as = as2[j], ad = ad2[j];
    int h = j >> 5;
#pragma unroll
    for (int r = 0; r < R; ++r) {
        int nn = n0 + r;
        if (nn < N) xh2[(size_t)nn * 128 + j] = acc[r];
        float va = acc[r] * as, vd = acc[r] * ad;
#pragma unroll
        for (int o = 16; o > 0; o >>= 1) {
            va += __shfl_xor(va, o, 32);
            vd += __shfl_xor(vd, o, 32);
        }
        if ((j & 31) == 0 && nn < N) { a_s[nn * 4 + h] = va; a_d[nn * 4 + h] = vd; }
    }
}

// Per-node segment softmax + weighted gather-aggregate, cooperative version.
// One block per node. Phase 1: per-edge logits (x4 heads) computed once into
// LDS (self-loop appended as edge deg). Phase 2: per-head max/exp/den,
// cooperative + shfl reduce. Phase 3: per-thread weighted gather of xh[src].
template <int CT, int C>
__global__ __launch_bounds__(CT) void agg_kernel(
        const int* __restrict__ off, const int* __restrict__ srcs,
        const float* __restrict__ aes, const float* __restrict__ aeloop,
        const float* __restrict__ a_s, const float* __restrict__ a_d,
        const float* __restrict__ xh, const float* __restrict__ bias,
        float* __restrict__ out, int relu) {
    constexpr int CAP = 512;        // max edges (incl. self) staged in LDS
    constexpr int NW  = CT / 64;    // waves per block
    constexpr int TPG = CT / 4;     // threads per head in phase 2
    __shared__ int   s_src[CAP];
    __shared__ float s_lg[CAP * 4];
    __shared__ float s_wred[NW * 4];
    __shared__ float s_m[4];
    __shared__ float s_den[4];

    int n = blockIdx.x;
    int j = threadIdx.x;
    int beg = off[n], end = off[n + 1];
    int deg = end - beg;
    int tot = deg + 1;  // + self loop
    int h = j / C;

    const float4 ad4 = *(const float4*)&a_d[(size_t)n * 4];

    if (tot <= CAP) {
        // ---- phase 1: logits, one edge per thread ----
        for (int idx = j; idx < tot; idx += CT) {
            int s; float4 ae;
            if (idx < deg) {
                s  = srcs[beg + idx];
                ae = *(const float4*)&aes[(size_t)(beg + idx) * 4];
            } else {
                s  = n;
                ae = *(const float4*)&aeloop[(size_t)n * 4];
            }
            s_src[idx] = s;
            float4 as4 = *(const float4*)&a_s[(size_t)s * 4];
            s_lg[idx * 4 + 0] = lrelu(as4.x + ad4.x + ae.x);
            s_lg[idx * 4 + 1] = lrelu(as4.y + ad4.y + ae.y);
            s_lg[idx * 4 + 2] = lrelu(as4.z + ad4.z + ae.z);
            s_lg[idx * 4 + 3] = lrelu(as4.w + ad4.w + ae.w);
        }
        __syncthreads();
        // ---- phase 2: per-head max, exp, denominator ----
        int lane = j & 63, w = j >> 6;
        int g = j & 3, r = j >> 2;
        float m = -3.4e38f;
        for (int i = r; i < tot; i += TPG) m = fmaxf(m, s_lg[i * 4 + g]);
#pragma unroll
        for (int o = 4; o < 64; o <<= 1) m = fmaxf(m, __shfl_xor(m, o, 64));
        if (lane < 4) s_wred[w * 4 + lane] = m;
        __syncthreads();
        if (j < 4) {
            float mm = s_wred[j];
            for (int ww = 1; ww < NW; ++ww) mm = fmaxf(mm, s_wred[ww * 4 + j]);
            s_m[j] = mm;
        }
        __syncthreads();
        float mh = s_m[g];
        float den = 0.f;
        for (int i = r; i < tot; i += TPG) {
            float e = expf(s_lg[i * 4 + g] - mh);
            s_lg[i * 4 + g] = e;
            den += e;
        }
#pragma unroll
        for (int o = 4; o < 64; o <<= 1) den += __shfl_xor(den, o, 64);
        if (lane < 4) s_wred[w * 4 + lane] = den;
        __syncthreads();
        if (j < 4) {
            float dd = s_wred[j];
            for (int ww = 1; ww < NW; ++ww) dd += s_wred[ww * 4 + j];
            s_den[j] = dd;
        }
        __syncthreads();
        // ---- phase 3: weighted gather ----
        float invden = 1.f / s_den[h];
        float acc = 0.f;
        int i = 0;
        for (; i + 1 < tot; i += 2) {
            float w0 = s_lg[i * 4 + h], w1 = s_lg[(i + 1) * 4 + h];
            int   s0 = s_src[i],        s1 = s_src[i + 1];
            float x0 = xh[(size_t)s0 * CT + j];
            float x1 = xh[(size_t)s1 * CT + j];
            acc += w0 * x0;
            acc += w1 * x1;
        }
        if (i < tot) acc += s_lg[i * 4 + h] * xh[(size_t)s_src[i] * CT + j];
        float o2 = acc * invden + bias[j];
        if (relu) o2 = fmaxf(o2, 0.f);
        out[(size_t)n * CT + j] = o2;
    } else {
        // ---- fallback (deg+1 > CAP): per-thread two-pass (correct, slow) ----
        float adh = ((const float*)&ad4)[h];
        float lself = lrelu(a_s[(size_t)n * 4 + h] + adh + aeloop[(size_t)n * 4 + h]);
        float m = lself;
        for (int i2 = beg; i2 < end; ++i2) {
            int s = srcs[i2];
            float lg = lrelu(a_s[(size_t)s * 4 + h] + adh + aes[(size_t)i2 * 4 + h]);
            m = fmaxf(m, lg);
        }
        float ex = expf(lself - m);
        float den = ex;
        float acc = ex * xh[(size_t)n * CT + j];
        for (int i2 = beg; i2 < end; ++i2) {
            int s = srcs[i2];
            float lg = lrelu(a_s[(size_t)s * 4 + h] + adh + aes[(size_t)i2 * 4 + h]);
            float e2 = expf(lg - m);
            den += e2;
            acc += e2 * xh[(size_t)s * CT + j];
        }
        float o2 = acc / den + bias[j];
        if (relu) o2 = fmaxf(o2, 0.f);
        out[(size_t)n * CT + j] = o2;
    }
}

extern "C" void kernel_launch(void* const* d_in, const int* in_sizes, int n_in,
                              void* d_out, int out_size, void* d_ws, size_t ws_size,
                              hipStream_t stream) {
    const float* x   = (const float*)d_in[0];
    const int*   ei  = (const int*)d_in[1];
    const float* ea  = (const float*)d_in[2];
    const float* W1  = (const float*)d_in[3];
    const float* We1 = (const float*)d_in[4];
    const float* as1 = (const float*)d_in[5];
    const float* ad1 = (const float*)d_in[6];
    const float* ae1 = (const float*)d_in[7];
    const float* b1  = (const float*)d_in[8];
    const float* W2  = (const float*)d_in[9];
    const float* We2 = (const float*)d_in[10];
    const float* as2 = (const float*)d_in[11];
    const float* ad2 = (const float*)d_in[12];
    const float* ae2 = (const float*)d_in[13];
    const float* b2  = (const float*)d_in[14];
    float* out = (float*)d_out;

    const int N = in_sizes[0] / 16;
    const int E = in_sizes[1] / 2;
    const int* srcp = ei;
    const int* dstp = ei + E;

    char* w = (char*)d_ws;
    size_t o = 0;
    auto alloc = [&](size_t bytes) -> void* {
        void* p = w + o;
        o += (bytes + 255) & ~(size_t)255;
        return p;
    };
    // zeroed prefix: cnt | fill (one memset covers both)
    int*   cnt     = (int*)alloc((size_t)N * 4);
    int*   fill    = (int*)alloc((size_t)N * 4);
    size_t zero_bytes = o;
    int*   off_    = (int*)alloc((size_t)(N + 1) * 4);
    float* Ve      = (float*)alloc(32 * 4);
    float* aeloop1 = (float*)alloc((size_t)N * 16);
    float* aeloop2 = (float*)alloc((size_t)N * 16);
    float* a_s1    = (float*)alloc((size_t)N * 16);
    float* a_d1    = (float*)alloc((size_t)N * 16);
    float* a_s2    = (float*)alloc((size_t)N * 16);
    float* a_d2    = (float*)alloc((size_t)N * 16);
    int*   src_s   = (int*)alloc((size_t)E * 4);
    float* ae1s    = (float*)alloc((size_t)E * 16);
    float* ae2s    = (float*)alloc((size_t)E * 16);
    float* xh1     = (float*)alloc((size_t)N * 256 * 4);
    float* h1      = (float*)alloc((size_t)N * 256 * 4);
    float* xh2     = xh1;  // xh1 dead after agg1; reuse for xh2 ([N,128] fits)

    hipMemsetAsync(d_ws, 0, zero_bytes, stream);
    ve_kernel<<<1, 64, 0, stream>>>(We1, ae1, We2, ae2, Ve);
    hist_kernel<<<(E + 255) / 256, 256, 0, stream>>>(dstp, cnt, E);
    scan_kernel<<<1, 1024, 0, stream>>>(cnt, off_, N);
    scatter_kernel<<<(E + 255) / 256, 256, 0, stream>>>(srcp, dstp, ea, off_, fill, Ve,
                                                        src_s, ae1s, ae2s, E);
    aeloop_kernel<<<(N * 8 + 255) / 256, 256, 0, stream>>>(off_, ae1s, ae2s,
                                                           aeloop1, aeloop2, N);
    // layer 1
    gemm1_kernel<<<(N + 7) / 8, 256, 0, stream>>>(x, W1, as1, ad1, xh1, a_s1, a_d1, N);
    agg_kernel<256, 64><<<N, 256, 0, stream>>>(off_, src_s, ae1s, aeloop1, a_s1, a_d1,
                                               xh1, b1, h1, 1);
    // layer 2
    gemm2_kernel<<<(N + 15) / 16, 128, 0, stream>>>(h1, W2, as2, ad2, xh2, a_s2, a_d2, N);
    agg_kernel<128, 32><<<N, 128, 0, stream>>>(off_, src_s, ae2s, aeloop2, a_s2, a_d2,
                                               xh2, b2, out, 0);
}

// Round 6
// 603.754 us; speedup vs baseline: 1.7298x; 1.1620x over previous
//
#include <hip/hip_runtime.h>
#include <hip/hip_bf16.h>

// GraphEncoder: 2-layer GATConv (edge_dim=4, heads=4, concat) on MI355X.
// N=50000, E=800000, IN=16, C1=64 (H*C1=256), C2=32 (H*C2=128).
//
// Key simplification: edge embeddings eh=ea@We only appear via dot with
// a_edge => precompute Ve[4x4] per layer, a_e = ea @ Ve. Never build eh.
//
// R1: agg_kernel cooperative (logits/exp once per edge-head in LDS) 322->189us.
// R4: hist float atomics removed; aeloop = segment-mean of ae (linearity).
// R5: (a) gather tables xh1/xh2 stored bf16 (halves the 870MB random-gather
//     traffic; f32 accumulate; h1/out stay f32). (b) single-block scan
//     (~20 barriers/chunk x 49 chunks on 1 CU) -> 3-phase multi-block scan.

#define NEG_SLOPE 0.2f

__device__ __forceinline__ float lrelu(float v) { return v > 0.f ? v : NEG_SLOPE * v; }

// Ve1[d][h] = sum_c We1[d, h*64+c] * ae1[h,c];  Ve2 likewise with C=32.
__global__ void ve_kernel(const float* __restrict__ We1, const float* __restrict__ ae1,
                          const float* __restrict__ We2, const float* __restrict__ ae2,
                          float* __restrict__ Ve) {
    int t = threadIdx.x;
    if (t < 16) {
        int d = t >> 2, h = t & 3;
        float s = 0.f;
        for (int c = 0; c < 64; ++c) s += We1[d * 256 + h * 64 + c] * ae1[h * 64 + c];
        Ve[t] = s;
    } else if (t < 32) {
        int tt = t - 16;
        int d = tt >> 2, h = tt & 3;
        float s = 0.f;
        for (int c = 0; c < 32; ++c) s += We2[d * 128 + h * 32 + c] * ae2[h * 32 + c];
        Ve[16 + tt] = s;
    }
}

// in-degree histogram only.
__global__ void hist_kernel(const int* __restrict__ dst, int* __restrict__ cnt, int E) {
    int e = blockIdx.x * blockDim.x + threadIdx.x;
    if (e >= E) return;
    atomicAdd(&cnt[dst[e]], 1);
}

// ---- 3-phase multi-block exclusive scan of cnt -> off ----
// Phase A: per-512-block inclusive scan (wave shfl + LDS wave-sum combine).
__global__ void blockscan_kernel(const int* __restrict__ cnt, int* __restrict__ off,
                                 int* __restrict__ bsum, int n) {
    __shared__ int wsum[8];
    int b = blockIdx.x, tid = threadIdx.x;
    int i = b * 512 + tid;
    int lane = tid & 63, w = tid >> 6;
    int v = (i < n) ? cnt[i] : 0;
    int s = v;
#pragma unroll
    for (int o = 1; o < 64; o <<= 1) {
        int t = __shfl_up(s, o, 64);
        if (lane >= o) s += t;
    }
    if (lane == 63) wsum[w] = s;
    __syncthreads();
    if (tid == 0) {
        int run = 0;
#pragma unroll
        for (int k = 0; k < 8; ++k) { int t = wsum[k]; wsum[k] = run; run += t; }
        bsum[b] = run;
    }
    __syncthreads();
    s += wsum[w];
    if (i < n) off[i + 1] = s;  // block-local inclusive; bsum added in phase C
}

// Phase B: exclusive scan of block sums (nb <= few hundred; serial is fine).
__global__ void bsumscan_kernel(int* __restrict__ bsum, int nb) {
    if (threadIdx.x == 0) {
        int run = 0;
        for (int k = 0; k < nb; ++k) { int t = bsum[k]; bsum[k] = run; run += t; }
    }
}

// Phase C: add block prefix; set off[0]=0.
__global__ void scanadd_kernel(const int* __restrict__ bsum, int* __restrict__ off, int n) {
    int i = blockIdx.x * 512 + threadIdx.x;
    if (i == 0) off[0] = 0;
    if (i < n) off[i + 1] += bsum[blockIdx.x];
}

// counting-sort edges by dst; store src and per-layer a_e at sorted position.
__global__ void scatter_kernel(const int* __restrict__ src, const int* __restrict__ dst,
                               const float* __restrict__ ea, const int* __restrict__ off,
                               int* __restrict__ fill, const float* __restrict__ Ve,
                               int* __restrict__ src_sorted, float* __restrict__ ae1s,
                               float* __restrict__ ae2s, int E) {
    int e = blockIdx.x * blockDim.x + threadIdx.x;
    if (e >= E) return;
    int d = dst[e];
    int pos = off[d] + atomicAdd(&fill[d], 1);
    src_sorted[pos] = src[e];
    float e4[4];
#pragma unroll
    for (int k = 0; k < 4; ++k) e4[k] = ea[e * 4 + k];
#pragma unroll
    for (int h = 0; h < 4; ++h) {
        float s1 = 0.f, s2 = 0.f;
#pragma unroll
        for (int k = 0; k < 4; ++k) { s1 += e4[k] * Ve[k * 4 + h]; s2 += e4[k] * Ve[16 + k * 4 + h]; }
        ae1s[pos * 4 + h] = s1;
        ae2s[pos * 4 + h] = s2;
    }
}

// aeloopL[n][h] = mean over n's incoming edges of aeLs (linearity of @Ve).
// 8 threads per node: k<4 -> layer1 head k, k>=4 -> layer2 head k-4.
__global__ void aeloop_kernel(const int* __restrict__ off,
                              const float* __restrict__ ae1s, const float* __restrict__ ae2s,
                              float* __restrict__ aeloop1, float* __restrict__ aeloop2, int n) {
    int t = blockIdx.x * blockDim.x + threadIdx.x;
    int node = t >> 3, k = t & 7;
    if (node >= n) return;
    int beg = off[node], end = off[node + 1];
    int deg = end - beg;
    float inv = 1.f / (float)(deg > 0 ? deg : 1);
    const float* srcp = (k < 4) ? ae1s : ae2s;
    int h = k & 3;
    float s = 0.f;
    for (int i = beg; i < end; ++i) s += srcp[(size_t)i * 4 + h];
    float* dstp = (k < 4) ? aeloop1 : aeloop2;
    dstp[(size_t)node * 4 + h] = s * inv;
}

// xh1 = x @ W1 ([N,16]@[16,256]) stored bf16; fused a_s1/a_d1 (f32 acc).
__global__ void gemm1_kernel(const float* __restrict__ x, const float* __restrict__ W1,
                             const float* __restrict__ as1, const float* __restrict__ ad1,
                             __hip_bfloat16* __restrict__ xh1, float* __restrict__ a_s,
                             float* __restrict__ a_d, int N) {
    constexpr int R = 8;
    __shared__ float sx[R * 16];
    int n0 = blockIdx.x * R;
    int j = threadIdx.x;
    for (int idx = j; idx < R * 16; idx += 256) {
        int r = idx >> 4, k = idx & 15;
        int nn = n0 + r;
        sx[idx] = (nn < N) ? x[nn * 16 + k] : 0.f;
    }
    __syncthreads();
    float acc[R];
#pragma unroll
    for (int r = 0; r < R; ++r) acc[r] = 0.f;
#pragma unroll
    for (int k = 0; k < 16; ++k) {
        float w = W1[k * 256 + j];
#pragma unroll
        for (int r = 0; r < R; ++r) acc[r] += sx[r * 16 + k] * w;
    }
    float as = as1[j], ad = ad1[j];
    int h = j >> 6;
#pragma unroll
    for (int r = 0; r < R; ++r) {
        int nn = n0 + r;
        if (nn < N) xh1[(size_t)nn * 256 + j] = __float2bfloat16(acc[r]);
        float va = acc[r] * as, vd = acc[r] * ad;
#pragma unroll
        for (int o = 32; o > 0; o >>= 1) {
            va += __shfl_xor(va, o, 64);
            vd += __shfl_xor(vd, o, 64);
        }
        if ((j & 63) == 0 && nn < N) { a_s[nn * 4 + h] = va; a_d[nn * 4 + h] = vd; }
    }
}

// xh2 = h1 @ W2 ([N,256]@[256,128]) stored bf16; fused a_s2/a_d2 (f32 acc).
__global__ void gemm2_kernel(const float* __restrict__ h1, const float* __restrict__ W2,
                             const float* __restrict__ as2, const float* __restrict__ ad2,
                             __hip_bfloat16* __restrict__ xh2, float* __restrict__ a_s,
                             float* __restrict__ a_d, int N) {
    constexpr int R = 16;
    __shared__ float sh[R * 256];
    int n0 = blockIdx.x * R;
    int j = threadIdx.x;
    for (int idx = j; idx < R * 256; idx += 128) {
        int r = idx >> 8, k = idx & 255;
        int nn = n0 + r;
        sh[idx] = (nn < N) ? h1[(size_t)nn * 256 + k] : 0.f;
    }
    __syncthreads();
    float acc[R];
#pragma unroll
    for (int r = 0; r < R; ++r) acc[r] = 0.f;
    for (int k = 0; k < 256; ++k) {
        float w = W2[k * 128 + j];
#pragma unroll
        for (int r = 0; r < R; ++r) acc[r] += sh[r * 256 + k] * w;
    }
    float as = as2[j], ad = ad2[j];
    int h = j >> 5;
#pragma unroll
    for (int r = 0; r < R; ++r) {
        int nn = n0 + r;
        if (nn < N) xh2[(size_t)nn * 128 + j] = __float2bfloat16(acc[r]);
        float va = acc[r] * as, vd = acc[r] * ad;
#pragma unroll
        for (int o = 16; o > 0; o >>= 1) {
            va += __shfl_xor(va, o, 32);
            vd += __shfl_xor(vd, o, 32);
        }
        if ((j & 31) == 0 && nn < N) { a_s[nn * 4 + h] = va; a_d[nn * 4 + h] = vd; }
    }
}

// Per-node segment softmax + weighted gather-aggregate (cooperative).
// xh gather table is bf16; accumulate f32.
template <int CT, int C>
__global__ __launch_bounds__(CT) void agg_kernel(
        const int* __restrict__ off, const int* __restrict__ srcs,
        const float* __restrict__ aes, const float* __restrict__ aeloop,
        const float* __restrict__ a_s, const float* __restrict__ a_d,
        const __hip_bfloat16* __restrict__ xh, const float* __restrict__ bias,
        float* __restrict__ out, int relu) {
    constexpr int CAP = 512;        // max edges (incl. self) staged in LDS
    constexpr int NW  = CT / 64;    // waves per block
    constexpr int TPG = CT / 4;     // threads per head in phase 2
    __shared__ int   s_src[CAP];
    __shared__ float s_lg[CAP * 4];
    __shared__ float s_wred[NW * 4];
    __shared__ float s_m[4];
    __shared__ float s_den[4];

    int n = blockIdx.x;
    int j = threadIdx.x;
    int beg = off[n], end = off[n + 1];
    int deg = end - beg;
    int tot = deg + 1;  // + self loop
    int h = j / C;

    const float4 ad4 = *(const float4*)&a_d[(size_t)n * 4];

    if (tot <= CAP) {
        // ---- phase 1: logits, one edge per thread ----
        for (int idx = j; idx < tot; idx += CT) {
            int s; float4 ae;
            if (idx < deg) {
                s  = srcs[beg + idx];
                ae = *(const float4*)&aes[(size_t)(beg + idx) * 4];
            } else {
                s  = n;
                ae = *(const float4*)&aeloop[(size_t)n * 4];
            }
            s_src[idx] = s;
            float4 as4 = *(const float4*)&a_s[(size_t)s * 4];
            s_lg[idx * 4 + 0] = lrelu(as4.x + ad4.x + ae.x);
            s_lg[idx * 4 + 1] = lrelu(as4.y + ad4.y + ae.y);
            s_lg[idx * 4 + 2] = lrelu(as4.z + ad4.z + ae.z);
            s_lg[idx * 4 + 3] = lrelu(as4.w + ad4.w + ae.w);
        }
        __syncthreads();
        // ---- phase 2: per-head max, exp, denominator ----
        int lane = j & 63, w = j >> 6;
        int g = j & 3, r = j >> 2;
        float m = -3.4e38f;
        for (int i = r; i < tot; i += TPG) m = fmaxf(m, s_lg[i * 4 + g]);
#pragma unroll
        for (int o = 4; o < 64; o <<= 1) m = fmaxf(m, __shfl_xor(m, o, 64));
        if (lane < 4) s_wred[w * 4 + lane] = m;
        __syncthreads();
        if (j < 4) {
            float mm = s_wred[j];
            for (int ww = 1; ww < NW; ++ww) mm = fmaxf(mm, s_wred[ww * 4 + j]);
            s_m[j] = mm;
        }
        __syncthreads();
        float mh = s_m[g];
        float den = 0.f;
        for (int i = r; i < tot; i += TPG) {
            float e = expf(s_lg[i * 4 + g] - mh);
            s_lg[i * 4 + g] = e;
            den += e;
        }
#pragma unroll
        for (int o = 4; o < 64; o <<= 1) den += __shfl_xor(den, o, 64);
        if (lane < 4) s_wred[w * 4 + lane] = den;
        __syncthreads();
        if (j < 4) {
            float dd = s_wred[j];
            for (int ww = 1; ww < NW; ++ww) dd += s_wred[ww * 4 + j];
            s_den[j] = dd;
        }
        __syncthreads();
        // ---- phase 3: weighted gather (bf16 loads, f32 fma) ----
        float invden = 1.f / s_den[h];
        float acc = 0.f;
        int i = 0;
        for (; i + 1 < tot; i += 2) {
            float w0 = s_lg[i * 4 + h], w1 = s_lg[(i + 1) * 4 + h];
            int   s0 = s_src[i],        s1 = s_src[i + 1];
            float x0 = __bfloat162float(xh[(size_t)s0 * CT + j]);
            float x1 = __bfloat162float(xh[(size_t)s1 * CT + j]);
            acc += w0 * x0;
            acc += w1 * x1;
        }
        if (i < tot) acc += s_lg[i * 4 + h] * __bfloat162float(xh[(size_t)s_src[i] * CT + j]);
        float o2 = acc * invden + bias[j];
        if (relu) o2 = fmaxf(o2, 0.f);
        out[(size_t)n * CT + j] = o2;
    } else {
        // ---- fallback (deg+1 > CAP): per-thread two-pass (correct, slow) ----
        float adh = ((const float*)&ad4)[h];
        float lself = lrelu(a_s[(size_t)n * 4 + h] + adh + aeloop[(size_t)n * 4 + h]);
        float m = lself;
        for (int i2 = beg; i2 < end; ++i2) {
            int s = srcs[i2];
            float lg = lrelu(a_s[(size_t)s * 4 + h] + adh + aes[(size_t)i2 * 4 + h]);
            m = fmaxf(m, lg);
        }
        float ex = expf(lself - m);
        float den = ex;
        float acc = ex * __bfloat162float(xh[(size_t)n * CT + j]);
        for (int i2 = beg; i2 < end; ++i2) {
            int s = srcs[i2];
            float lg = lrelu(a_s[(size_t)s * 4 + h] + adh + aes[(size_t)i2 * 4 + h]);
            float e2 = expf(lg - m);
            den += e2;
            acc += e2 * __bfloat162float(xh[(size_t)s * CT + j]);
        }
        float o2 = acc / den + bias[j];
        if (relu) o2 = fmaxf(o2, 0.f);
        out[(size_t)n * CT + j] = o2;
    }
}

extern "C" void kernel_launch(void* const* d_in, const int* in_sizes, int n_in,
                              void* d_out, int out_size, void* d_ws, size_t ws_size,
                              hipStream_t stream) {
    const float* x   = (const float*)d_in[0];
    const int*   ei  = (const int*)d_in[1];
    const float* ea  = (const float*)d_in[2];
    const float* W1  = (const float*)d_in[3];
    const float* We1 = (const float*)d_in[4];
    const float* as1 = (const float*)d_in[5];
    const float* ad1 = (const float*)d_in[6];
    const float* ae1 = (const float*)d_in[7];
    const float* b1  = (const float*)d_in[8];
    const float* W2  = (const float*)d_in[9];
    const float* We2 = (const float*)d_in[10];
    const float* as2 = (const float*)d_in[11];
    const float* ad2 = (const float*)d_in[12];
    const float* ae2 = (const float*)d_in[13];
    const float* b2  = (const float*)d_in[14];
    float* out = (float*)d_out;

    const int N = in_sizes[0] / 16;
    const int E = in_sizes[1] / 2;
    const int* srcp = ei;
    const int* dstp = ei + E;
    const int NB = (N + 511) / 512;

    char* w = (char*)d_ws;
    size_t o = 0;
    auto alloc = [&](size_t bytes) -> void* {
        void* p = w + o;
        o += (bytes + 255) & ~(size_t)255;
        return p;
    };
    // zeroed prefix: cnt | fill (one memset covers both)
    int*   cnt     = (int*)alloc((size_t)N * 4);
    int*   fill    = (int*)alloc((size_t)N * 4);
    size_t zero_bytes = o;
    int*   off_    = (int*)alloc((size_t)(N + 1) * 4);
    int*   bsum    = (int*)alloc((size_t)NB * 4);
    float* Ve      = (float*)alloc(32 * 4);
    float* aeloop1 = (float*)alloc((size_t)N * 16);
    float* aeloop2 = (float*)alloc((size_t)N * 16);
    float* a_s1    = (float*)alloc((size_t)N * 16);
    float* a_d1    = (float*)alloc((size_t)N * 16);
    float* a_s2    = (float*)alloc((size_t)N * 16);
    float* a_d2    = (float*)alloc((size_t)N * 16);
    int*   src_s   = (int*)alloc((size_t)E * 4);
    float* ae1s    = (float*)alloc((size_t)E * 16);
    float* ae2s    = (float*)alloc((size_t)E * 16);
    __hip_bfloat16* xh1 = (__hip_bfloat16*)alloc((size_t)N * 256 * 2);
    float* h1      = (float*)alloc((size_t)N * 256 * 4);
    __hip_bfloat16* xh2 = xh1;  // xh1 dead after agg1; reuse ([N,128] bf16 fits)

    hipMemsetAsync(d_ws, 0, zero_bytes, stream);
    ve_kernel<<<1, 64, 0, stream>>>(We1, ae1, We2, ae2, Ve);
    hist_kernel<<<(E + 255) / 256, 256, 0, stream>>>(dstp, cnt, E);
    blockscan_kernel<<<NB, 512, 0, stream>>>(cnt, off_, bsum, N);
    bsumscan_kernel<<<1, 64, 0, stream>>>(bsum, NB);
    scanadd_kernel<<<NB, 512, 0, stream>>>(bsum, off_, N);
    scatter_kernel<<<(E + 255) / 256, 256, 0, stream>>>(srcp, dstp, ea, off_, fill, Ve,
                                                        src_s, ae1s, ae2s, E);
    aeloop_kernel<<<(N * 8 + 255) / 256, 256, 0, stream>>>(off_, ae1s, ae2s,
                                                           aeloop1, aeloop2, N);
    // layer 1
    gemm1_kernel<<<(N + 7) / 8, 256, 0, stream>>>(x, W1, as1, ad1, xh1, a_s1, a_d1, N);
    agg_kernel<256, 64><<<N, 256, 0, stream>>>(off_, src_s, ae1s, aeloop1, a_s1, a_d1,
                                               xh1, b1, h1, 1);
    // layer 2
    gemm2_kernel<<<(N + 15) / 16, 128, 0, stream>>>(h1, W2, as2, ad2, xh2, a_s2, a_d2, N);
    agg_kernel<128, 32><<<N, 128, 0, stream>>>(off_, src_s, ae2s, aeloop2, a_s2, a_d2,
                                               xh2, b2, out, 0);
}

// Round 12
// 537.776 us; speedup vs baseline: 1.9421x; 1.1227x over previous
//
#include <hip/hip_runtime.h>
#include <hip/hip_bf16.h>

// GraphEncoder: 2-layer GATConv (edge_dim=4, heads=4, concat) on MI355X.
// N=50000, E=800000, IN=16, C1=64 (H*C1=256), C2=32 (H*C2=128).
//
// Key simplification: edge embeddings eh=ea@We only appear via dot with
// a_edge => precompute Ve[4x4] per layer, a_e = ea @ Ve. Never build eh.
//
// R1: agg cooperative (logits/exp once per edge-head in LDS) 322->189us.
// R4: hist float atomics removed; aeloop = segment-mean of ae (linearity).
// R5: bf16 gather tables (FETCH 448->230MB, dur only -10% => latency-bound,
//     not BW-bound); multi-block scan.
// R6: agg phase-3 gather: ushort2 loads (2ch/thread, 4B/lane), unroll x4
//     (4 gathers in flight), CAP 512->96 (LDS 14.8KB->2KB).
// R7-R11: infra timeouts — resubmitting R6 source unchanged for measurement.

#define NEG_SLOPE 0.2f

__device__ __forceinline__ float lrelu(float v) { return v > 0.f ? v : NEG_SLOPE * v; }
__device__ __forceinline__ float bf_lo(unsigned v) { return __uint_as_float(v << 16); }
__device__ __forceinline__ float bf_hi(unsigned v) { return __uint_as_float(v & 0xffff0000u); }

// Ve1[d][h] = sum_c We1[d, h*64+c] * ae1[h,c];  Ve2 likewise with C=32.
__global__ void ve_kernel(const float* __restrict__ We1, const float* __restrict__ ae1,
                          const float* __restrict__ We2, const float* __restrict__ ae2,
                          float* __restrict__ Ve) {
    int t = threadIdx.x;
    if (t < 16) {
        int d = t >> 2, h = t & 3;
        float s = 0.f;
        for (int c = 0; c < 64; ++c) s += We1[d * 256 + h * 64 + c] * ae1[h * 64 + c];
        Ve[t] = s;
    } else if (t < 32) {
        int tt = t - 16;
        int d = tt >> 2, h = tt & 3;
        float s = 0.f;
        for (int c = 0; c < 32; ++c) s += We2[d * 128 + h * 32 + c] * ae2[h * 32 + c];
        Ve[16 + tt] = s;
    }
}

// in-degree histogram only.
__global__ void hist_kernel(const int* __restrict__ dst, int* __restrict__ cnt, int E) {
    int e = blockIdx.x * blockDim.x + threadIdx.x;
    if (e >= E) return;
    atomicAdd(&cnt[dst[e]], 1);
}

// ---- 3-phase multi-block exclusive scan of cnt -> off ----
__global__ void blockscan_kernel(const int* __restrict__ cnt, int* __restrict__ off,
                                 int* __restrict__ bsum, int n) {
    __shared__ int wsum[8];
    int b = blockIdx.x, tid = threadIdx.x;
    int i = b * 512 + tid;
    int lane = tid & 63, w = tid >> 6;
    int v = (i < n) ? cnt[i] : 0;
    int s = v;
#pragma unroll
    for (int o = 1; o < 64; o <<= 1) {
        int t = __shfl_up(s, o, 64);
        if (lane >= o) s += t;
    }
    if (lane == 63) wsum[w] = s;
    __syncthreads();
    if (tid == 0) {
        int run = 0;
#pragma unroll
        for (int k = 0; k < 8; ++k) { int t = wsum[k]; wsum[k] = run; run += t; }
        bsum[b] = run;
    }
    __syncthreads();
    s += wsum[w];
    if (i < n) off[i + 1] = s;  // block-local inclusive; bsum added in phase C
}

__global__ void bsumscan_kernel(int* __restrict__ bsum, int nb) {
    if (threadIdx.x == 0) {
        int run = 0;
        for (int k = 0; k < nb; ++k) { int t = bsum[k]; bsum[k] = run; run += t; }
    }
}

__global__ void scanadd_kernel(const int* __restrict__ bsum, int* __restrict__ off, int n) {
    int i = blockIdx.x * 512 + threadIdx.x;
    if (i == 0) off[0] = 0;
    if (i < n) off[i + 1] += bsum[blockIdx.x];
}

// counting-sort edges by dst; store src and per-layer a_e at sorted position.
__global__ void scatter_kernel(const int* __restrict__ src, const int* __restrict__ dst,
                               const float* __restrict__ ea, const int* __restrict__ off,
                               int* __restrict__ fill, const float* __restrict__ Ve,
                               int* __restrict__ src_sorted, float* __restrict__ ae1s,
                               float* __restrict__ ae2s, int E) {
    int e = blockIdx.x * blockDim.x + threadIdx.x;
    if (e >= E) return;
    int d = dst[e];
    int pos = off[d] + atomicAdd(&fill[d], 1);
    src_sorted[pos] = src[e];
    float e4[4];
#pragma unroll
    for (int k = 0; k < 4; ++k) e4[k] = ea[e * 4 + k];
#pragma unroll
    for (int h = 0; h < 4; ++h) {
        float s1 = 0.f, s2 = 0.f;
#pragma unroll
        for (int k = 0; k < 4; ++k) { s1 += e4[k] * Ve[k * 4 + h]; s2 += e4[k] * Ve[16 + k * 4 + h]; }
        ae1s[pos * 4 + h] = s1;
        ae2s[pos * 4 + h] = s2;
    }
}

// aeloopL[n][h] = mean over n's incoming edges of aeLs (linearity of @Ve).
__global__ void aeloop_kernel(const int* __restrict__ off,
                              const float* __restrict__ ae1s, const float* __restrict__ ae2s,
                              float* __restrict__ aeloop1, float* __restrict__ aeloop2, int n) {
    int t = blockIdx.x * blockDim.x + threadIdx.x;
    int node = t >> 3, k = t & 7;
    if (node >= n) return;
    int beg = off[node], end = off[node + 1];
    int deg = end - beg;
    float inv = 1.f / (float)(deg > 0 ? deg : 1);
    const float* srcp = (k < 4) ? ae1s : ae2s;
    int h = k & 3;
    float s = 0.f;
    for (int i = beg; i < end; ++i) s += srcp[(size_t)i * 4 + h];
    float* dstp = (k < 4) ? aeloop1 : aeloop2;
    dstp[(size_t)node * 4 + h] = s * inv;
}

// xh1 = x @ W1 ([N,16]@[16,256]) stored bf16; fused a_s1/a_d1 (f32 acc).
__global__ void gemm1_kernel(const float* __restrict__ x, const float* __restrict__ W1,
                             const float* __restrict__ as1, const float* __restrict__ ad1,
                             __hip_bfloat16* __restrict__ xh1, float* __restrict__ a_s,
                             float* __restrict__ a_d, int N) {
    constexpr int R = 8;
    __shared__ float sx[R * 16];
    int n0 = blockIdx.x * R;
    int j = threadIdx.x;
    for (int idx = j; idx < R * 16; idx += 256) {
        int r = idx >> 4, k = idx & 15;
        int nn = n0 + r;
        sx[idx] = (nn < N) ? x[nn * 16 + k] : 0.f;
    }
    __syncthreads();
    float acc[R];
#pragma unroll
    for (int r = 0; r < R; ++r) acc[r] = 0.f;
#pragma unroll
    for (int k = 0; k < 16; ++k) {
        float w = W1[k * 256 + j];
#pragma unroll
        for (int r = 0; r < R; ++r) acc[r] += sx[r * 16 + k] * w;
    }
    float as = as1[j], ad = ad1[j];
    int h = j >> 6;
#pragma unroll
    for (int r = 0; r < R; ++r) {
        int nn = n0 + r;
        if (nn < N) xh1[(size_t)nn * 256 + j] = __float2bfloat16(acc[r]);
        float va = acc[r] * as, vd = acc[r] * ad;
#pragma unroll
        for (int o = 32; o > 0; o >>= 1) {
            va += __shfl_xor(va, o, 64);
            vd += __shfl_xor(vd, o, 64);
        }
        if ((j & 63) == 0 && nn < N) { a_s[nn * 4 + h] = va; a_d[nn * 4 + h] = vd; }
    }
}

// xh2 = h1 @ W2 ([N,256]@[256,128]) stored bf16; fused a_s2/a_d2 (f32 acc).
__global__ void gemm2_kernel(const float* __restrict__ h1, const float* __restrict__ W2,
                             const float* __restrict__ as2, const float* __restrict__ ad2,
                             __hip_bfloat16* __restrict__ xh2, float* __restrict__ a_s,
                             float* __restrict__ a_d, int N) {
    constexpr int R = 16;
    __shared__ float sh[R * 256];
    int n0 = blockIdx.x * R;
    int j = threadIdx.x;
    for (int idx = j; idx < R * 256; idx += 128) {
        int r = idx >> 8, k = idx & 255;
        int nn = n0 + r;
        sh[idx] = (nn < N) ? h1[(size_t)nn * 256 + k] : 0.f;
    }
    __syncthreads();
    float acc[R];
#pragma unroll
    for (int r = 0; r < R; ++r) acc[r] = 0.f;
    for (int k = 0; k < 256; ++k) {
        float w = W2[k * 128 + j];
#pragma unroll
        for (int r = 0; r < R; ++r) acc[r] += sh[r * 256 + k] * w;
    }
    float as = as2[j], ad = ad2[j];
    int h = j >> 5;
#pragma unroll
    for (int r = 0; r < R; ++r) {
        int nn = n0 + r;
        if (nn < N) xh2[(size_t)nn * 128 + j] = __float2bfloat16(acc[r]);
        float va = acc[r] * as, vd = acc[r] * ad;
#pragma unroll
        for (int o = 16; o > 0; o >>= 1) {
            va += __shfl_xor(va, o, 32);
            vd += __shfl_xor(vd, o, 32);
        }
        if ((j & 31) == 0 && nn < N) { a_s[nn * 4 + h] = va; a_d[nn * 4 + h] = vd; }
    }
}

// Per-node segment softmax + weighted gather-aggregate (cooperative).
// CT threads, CH channels, CPT = CH/CT channels per thread (1 or 2).
// Phase 3 gather: CPT==2 -> one 4B uint (2 bf16) per edge per thread;
// unrolled x4 for 4 loads in flight.
template <int CT, int CH>
__global__ __launch_bounds__(CT) void agg_kernel(
        const int* __restrict__ off, const int* __restrict__ srcs,
        const float* __restrict__ aes, const float* __restrict__ aeloop,
        const float* __restrict__ a_s, const float* __restrict__ a_d,
        const __hip_bfloat16* __restrict__ xh, const float* __restrict__ bias,
        float* __restrict__ out, int relu) {
    constexpr int CPT = CH / CT;    // channels per thread (1 or 2)
    constexpr int C   = CH / 4;     // channels per head
    constexpr int CAP = 96;         // max edges (incl. self) staged in LDS
    constexpr int NW  = CT / 64;    // waves per block
    constexpr int TPG = CT / 4;     // threads per head in phase 2
    __shared__ int   s_src[CAP];
    __shared__ float s_lg[CAP * 4];
    __shared__ float s_wred[NW * 4];
    __shared__ float s_m[4];
    __shared__ float s_den[4];

    int n = blockIdx.x;
    int j = threadIdx.x;
    int beg = off[n], end = off[n + 1];
    int deg = end - beg;
    int tot = deg + 1;  // + self loop
    int h = (j * CPT) / C;

    const float4 ad4 = *(const float4*)&a_d[(size_t)n * 4];

    if (tot <= CAP) {
        // ---- phase 1: logits, one edge per thread ----
        for (int idx = j; idx < tot; idx += CT) {
            int s; float4 ae;
            if (idx < deg) {
                s  = srcs[beg + idx];
                ae = *(const float4*)&aes[(size_t)(beg + idx) * 4];
            } else {
                s  = n;
                ae = *(const float4*)&aeloop[(size_t)n * 4];
            }
            s_src[idx] = s;
            float4 as4 = *(const float4*)&a_s[(size_t)s * 4];
            s_lg[idx * 4 + 0] = lrelu(as4.x + ad4.x + ae.x);
            s_lg[idx * 4 + 1] = lrelu(as4.y + ad4.y + ae.y);
            s_lg[idx * 4 + 2] = lrelu(as4.z + ad4.z + ae.z);
            s_lg[idx * 4 + 3] = lrelu(as4.w + ad4.w + ae.w);
        }
        __syncthreads();
        // ---- phase 2: per-head max, exp, denominator ----
        int lane = j & 63, w = j >> 6;
        int g = j & 3, r = j >> 2;
        float m = -3.4e38f;
        for (int i = r; i < tot; i += TPG) m = fmaxf(m, s_lg[i * 4 + g]);
#pragma unroll
        for (int o = 4; o < 64; o <<= 1) m = fmaxf(m, __shfl_xor(m, o, 64));
        if (lane < 4) s_wred[w * 4 + lane] = m;
        __syncthreads();
        if (j < 4) {
            float mm = s_wred[j];
            for (int ww = 1; ww < NW; ++ww) mm = fmaxf(mm, s_wred[ww * 4 + j]);
            s_m[j] = mm;
        }
        __syncthreads();
        float mh = s_m[g];
        float den = 0.f;
        for (int i = r; i < tot; i += TPG) {
            float e = expf(s_lg[i * 4 + g] - mh);
            s_lg[i * 4 + g] = e;
            den += e;
        }
#pragma unroll
        for (int o = 4; o < 64; o <<= 1) den += __shfl_xor(den, o, 64);
        if (lane < 4) s_wred[w * 4 + lane] = den;
        __syncthreads();
        if (j < 4) {
            float dd = s_wred[j];
            for (int ww = 1; ww < NW; ++ww) dd += s_wred[ww * 4 + j];
            s_den[j] = dd;
        }
        __syncthreads();
        // ---- phase 3: weighted gather (unroll x4, wide loads) ----
        float invden = 1.f / s_den[h];
        if constexpr (CPT == 2) {
            const unsigned* xu = (const unsigned*)xh;
            constexpr int CHW = CH / 2;
            float a0 = 0.f, a1 = 0.f;
            int i = 0;
            for (; i + 4 <= tot; i += 4) {
                float w0 = s_lg[(i+0)*4+h], w1 = s_lg[(i+1)*4+h];
                float w2 = s_lg[(i+2)*4+h], w3 = s_lg[(i+3)*4+h];
                int s0 = s_src[i+0], s1 = s_src[i+1], s2 = s_src[i+2], s3 = s_src[i+3];
                unsigned v0 = xu[(size_t)s0 * CHW + j];
                unsigned v1 = xu[(size_t)s1 * CHW + j];
                unsigned v2 = xu[(size_t)s2 * CHW + j];
                unsigned v3 = xu[(size_t)s3 * CHW + j];
                a0 += w0 * bf_lo(v0); a1 += w0 * bf_hi(v0);
                a0 += w1 * bf_lo(v1); a1 += w1 * bf_hi(v1);
                a0 += w2 * bf_lo(v2); a1 += w2 * bf_hi(v2);
                a0 += w3 * bf_lo(v3); a1 += w3 * bf_hi(v3);
            }
            for (; i < tot; ++i) {
                float ww = s_lg[i * 4 + h];
                unsigned v = xu[(size_t)s_src[i] * CHW + j];
                a0 += ww * bf_lo(v); a1 += ww * bf_hi(v);
            }
            float2 bb = ((const float2*)bias)[j];
            float o0 = a0 * invden + bb.x;
            float o1 = a1 * invden + bb.y;
            if (relu) { o0 = fmaxf(o0, 0.f); o1 = fmaxf(o1, 0.f); }
            ((float2*)&out[(size_t)n * CH])[j] = make_float2(o0, o1);
        } else {
            const unsigned short* xs = (const unsigned short*)xh;
            float a0 = 0.f;
            int i = 0;
            for (; i + 4 <= tot; i += 4) {
                float w0 = s_lg[(i+0)*4+h], w1 = s_lg[(i+1)*4+h];
                float w2 = s_lg[(i+2)*4+h], w3 = s_lg[(i+3)*4+h];
                int s0 = s_src[i+0], s1 = s_src[i+1], s2 = s_src[i+2], s3 = s_src[i+3];
                float x0 = __uint_as_float((unsigned)xs[(size_t)s0 * CH + j] << 16);
                float x1 = __uint_as_float((unsigned)xs[(size_t)s1 * CH + j] << 16);
                float x2 = __uint_as_float((unsigned)xs[(size_t)s2 * CH + j] << 16);
                float x3 = __uint_as_float((unsigned)xs[(size_t)s3 * CH + j] << 16);
                a0 += w0 * x0; a0 += w1 * x1; a0 += w2 * x2; a0 += w3 * x3;
            }
            for (; i < tot; ++i)
                a0 += s_lg[i * 4 + h] *
                      __uint_as_float((unsigned)xs[(size_t)s_src[i] * CH + j] << 16);
            float o2 = a0 * invden + bias[j];
            if (relu) o2 = fmaxf(o2, 0.f);
            out[(size_t)n * CH + j] = o2;
        }
    } else {
        // ---- fallback (deg+1 > CAP): per-thread two-pass (correct, slow) ----
        for (int c = j * CPT; c < (j + 1) * CPT; ++c) {
            int hh = c / C;
            float adh = ((const float*)&ad4)[hh];
            float lself = lrelu(a_s[(size_t)n * 4 + hh] + adh + aeloop[(size_t)n * 4 + hh]);
            float m = lself;
            for (int i2 = beg; i2 < end; ++i2) {
                int s = srcs[i2];
                float lg = lrelu(a_s[(size_t)s * 4 + hh] + adh + aes[(size_t)i2 * 4 + hh]);
                m = fmaxf(m, lg);
            }
            float ex = expf(lself - m);
            float den = ex;
            float acc = ex * __bfloat162float(xh[(size_t)n * CH + c]);
            for (int i2 = beg; i2 < end; ++i2) {
                int s = srcs[i2];
                float lg = lrelu(a_s[(size_t)s * 4 + hh] + adh + aes[(size_t)i2 * 4 + hh]);
                float e2 = expf(lg - m);
                den += e2;
                acc += e2 * __bfloat162float(xh[(size_t)s * CH + c]);
            }
            float o2 = acc / den + bias[c];
            if (relu) o2 = fmaxf(o2, 0.f);
            out[(size_t)n * CH + c] = o2;
        }
    }
}

extern "C" void kernel_launch(void* const* d_in, const int* in_sizes, int n_in,
                              void* d_out, int out_size, void* d_ws, size_t ws_size,
                              hipStream_t stream) {
    const float* x   = (const float*)d_in[0];
    const int*   ei  = (const int*)d_in[1];
    const float* ea  = (const float*)d_in[2];
    const float* W1  = (const float*)d_in[3];
    const float* We1 = (const float*)d_in[4];
    const float* as1 = (const float*)d_in[5];
    const float* ad1 = (const float*)d_in[6];
    const float* ae1 = (const float*)d_in[7];
    const float* b1  = (const float*)d_in[8];
    const float* W2  = (const float*)d_in[9];
    const float* We2 = (const float*)d_in[10];
    const float* as2 = (const float*)d_in[11];
    const float* ad2 = (const float*)d_in[12];
    const float* ae2 = (const float*)d_in[13];
    const float* b2  = (const float*)d_in[14];
    float* out = (float*)d_out;

    const int N = in_sizes[0] / 16;
    const int E = in_sizes[1] / 2;
    const int* srcp = ei;
    const int* dstp = ei + E;
    const int NB = (N + 511) / 512;

    char* w = (char*)d_ws;
    size_t o = 0;
    auto alloc = [&](size_t bytes) -> void* {
        void* p = w + o;
        o += (bytes + 255) & ~(size_t)255;
        return p;
    };
    // zeroed prefix: cnt | fill (one memset covers both)
    int*   cnt     = (int*)alloc((size_t)N * 4);
    int*   fill    = (int*)alloc((size_t)N * 4);
    size_t zero_bytes = o;
    int*   off_    = (int*)alloc((size_t)(N + 1) * 4);
    int*   bsum    = (int*)alloc((size_t)NB * 4);
    float* Ve      = (float*)alloc(32 * 4);
    float* aeloop1 = (float*)alloc((size_t)N * 16);
    float* aeloop2 = (float*)alloc((size_t)N * 16);
    float* a_s1    = (float*)alloc((size_t)N * 16);
    float* a_d1    = (float*)alloc((size_t)N * 16);
    float* a_s2    = (float*)alloc((size_t)N * 16);
    float* a_d2    = (float*)alloc((size_t)N * 16);
    int*   src_s   = (int*)alloc((size_t)E * 4);
    float* ae1s    = (float*)alloc((size_t)E * 16);
    float* ae2s    = (float*)alloc((size_t)E * 16);
    __hip_bfloat16* xh1 = (__hip_bfloat16*)alloc((size_t)N * 256 * 2);
    float* h1      = (float*)alloc((size_t)N * 256 * 4);
    __hip_bfloat16* xh2 = xh1;  // xh1 dead after agg1; reuse ([N,128] bf16 fits)

    hipMemsetAsync(d_ws, 0, zero_bytes, stream);
    ve_kernel<<<1, 64, 0, stream>>>(We1, ae1, We2, ae2, Ve);
    hist_kernel<<<(E + 255) / 256, 256, 0, stream>>>(dstp, cnt, E);
    blockscan_kernel<<<NB, 512, 0, stream>>>(cnt, off_, bsum, N);
    bsumscan_kernel<<<1, 64, 0, stream>>>(bsum, NB);
    scanadd_kernel<<<NB, 512, 0, stream>>>(bsum, off_, N);
    scatter_kernel<<<(E + 255) / 256, 256, 0, stream>>>(srcp, dstp, ea, off_, fill, Ve,
                                                        src_s, ae1s, ae2s, E);
    aeloop_kernel<<<(N * 8 + 255) / 256, 256, 0, stream>>>(off_, ae1s, ae2s,
                                                           aeloop1, aeloop2, N);
    // layer 1
    gemm1_kernel<<<(N + 7) / 8, 256, 0, stream>>>(x, W1, as1, ad1, xh1, a_s1, a_d1, N);
    agg_kernel<128, 256><<<N, 128, 0, stream>>>(off_, src_s, ae1s, aeloop1, a_s1, a_d1,
                                                xh1, b1, h1, 1);
    // layer 2
    gemm2_kernel<<<(N + 15) / 16, 128, 0, stream>>>(h1, W2, as2, ad2, xh2, a_s2, a_d2, N);
    agg_kernel<128, 128><<<N, 128, 0, stream>>>(off_, src_s, ae2s, aeloop2, a_s2, a_d2,
                                                xh2, b2, out, 0);
}